// Round 3
// baseline (500.000 us; speedup 1.0000x reference)
//
#include <hip/hip_runtime.h>

typedef __attribute__((ext_vector_type(8))) short bf16x8;
typedef __attribute__((ext_vector_type(4))) float f32x4;
typedef __attribute__((ext_vector_type(4))) int int4v;
typedef __attribute__((ext_vector_type(4))) unsigned short us4;

#define LOG2E 1.4426950408889634f

__device__ __forceinline__ unsigned short f2b(float f){
  unsigned u = __builtin_bit_cast(unsigned, f);
  u = (u + 0x7fffu + ((u >> 16) & 1u)) >> 16;
  return (unsigned short)u;
}
// round-to-nearest (ties up) — 0.5 ulp, 2 VALU ops
__device__ __forceinline__ unsigned short f2bf(float f){
  unsigned u = __builtin_bit_cast(unsigned, f);
  return (unsigned short)((u + 0x8000u) >> 16);
}

__device__ __forceinline__ f32x4 mfma16(bf16x8 a, bf16x8 b, f32x4 c){
  return __builtin_amdgcn_mfma_f32_16x16x32_bf16(a, b, c, 0, 0, 0);
}

// ---------------- cast fp32 -> bf16 (vectorized) ----------------
__global__ __launch_bounds__(256) void cast_bf16_kernel(const float4* __restrict__ in,
                                                        us4* __restrict__ out, int n4){
  int i = blockIdx.x * 256 + threadIdx.x;
  int stride = gridDim.x * 256;
  for (; i < n4; i += stride){
    float4 v = in[i];
    us4 o; o.x = f2b(v.x); o.y = f2b(v.y); o.z = f2b(v.z); o.w = f2b(v.w);
    out[i] = o;
  }
}

// ---------------- transpose + cast: in[R][C] fp32 -> out[C][R] bf16 ----------------
__global__ __launch_bounds__(256) void transpose_cast_kernel(const float* __restrict__ in,
                                                             unsigned short* __restrict__ out,
                                                             int R, int C){
  __shared__ float tile[64][65];
  const int tid = threadIdx.x;
  const int c0 = blockIdx.x * 64, r0 = blockIdx.y * 64;
#pragma unroll
  for (int p = 0; p < 4; p++){
    int idx = p * 1024 + tid * 4;
    int rr = idx >> 6, cc = idx & 63;
    float4 v = *(const float4*)(in + (size_t)(r0 + rr) * C + (c0 + cc));
    tile[rr][cc+0] = v.x; tile[rr][cc+1] = v.y; tile[rr][cc+2] = v.z; tile[rr][cc+3] = v.w;
  }
  __syncthreads();
#pragma unroll
  for (int p = 0; p < 4; p++){
    int idx = p * 1024 + tid * 4;
    int crow = idx >> 6, rcol = idx & 63;
    us4 o;
    o.x = f2b(tile[rcol+0][crow]); o.y = f2b(tile[rcol+1][crow]);
    o.z = f2b(tile[rcol+2][crow]); o.w = f2b(tile[rcol+3][crow]);
    *(us4*)(out + (size_t)(c0 + crow) * R + (r0 + rcol)) = o;
  }
}

// ---------------- bf16 GEMM: C[M][N] = A[M][K] * BT[N][K]^T + bias ----------------
template<int MODE>
__global__ __launch_bounds__(256, 2) void gemm_kernel(
    const unsigned short* __restrict__ A,
    const unsigned short* __restrict__ BT,
    const float* __restrict__ bias,
    unsigned short* __restrict__ qb,
    unsigned short* __restrict__ kb,
    unsigned short* __restrict__ vtb,
    float* __restrict__ outp)
{
  constexpr int K = 2048;
  constexpr int NT = K / 64;
  __shared__ short lA[2][128 * 64];
  __shared__ short lB[2][128 * 64];
  const int tid = threadIdx.x, lane = tid & 63, wid = tid >> 6;
  const int l16 = lane & 15, lhi = lane >> 4;
  const int wr = wid >> 1, wc = wid & 1;
  const int bm = blockIdx.x, bn = blockIdx.y;

  const unsigned short* Abase = A + (size_t)bm * 128 * K;
  const unsigned short* Bbase = BT + (size_t)bn * 128 * K;

  int4v areg[4], breg[4];

  auto stage_load = [&](int kt){
#pragma unroll
    for (int i = 0; i < 4; i++){
      int c = tid + 256 * i;
      int row = c >> 3; int off8 = (c & 7) * 8;
      areg[i] = *(const int4v*)(Abase + (size_t)row * K + kt * 64 + off8);
      breg[i] = *(const int4v*)(Bbase + (size_t)row * K + kt * 64 + off8);
    }
  };
  auto stage_write = [&](int buf){
#pragma unroll
    for (int i = 0; i < 4; i++){
      int c = tid + 256 * i;
      int row = c >> 3;
      int byte = (row * 128 + (c & 7) * 16) ^ ((row & 7) << 4);
      *(int4v*)((char*)lA[buf] + byte) = areg[i];
      *(int4v*)((char*)lB[buf] + byte) = breg[i];
    }
  };

  f32x4 acc[4][4];
  f32x4 z = {0.f, 0.f, 0.f, 0.f};
#pragma unroll
  for (int i = 0; i < 4; i++)
#pragma unroll
    for (int j = 0; j < 4; j++) acc[i][j] = z;

  stage_load(0); stage_write(0); __syncthreads();
  int cur = 0;
  for (int kt = 0; kt < NT; ++kt){
    if (kt + 1 < NT) stage_load(kt + 1);
#pragma unroll
    for (int kk = 0; kk < 2; kk++){
      bf16x8 af[4], bfr[4];
#pragma unroll
      for (int mf = 0; mf < 4; mf++){
        int row = wr * 64 + mf * 16 + l16;
        int byte = (row * 128 + kk * 64 + lhi * 16) ^ ((row & 7) << 4);
        af[mf] = *(const bf16x8*)((const char*)lA[cur] + byte);
      }
#pragma unroll
      for (int nf = 0; nf < 4; nf++){
        int row = wc * 64 + nf * 16 + l16;
        int byte = (row * 128 + kk * 64 + lhi * 16) ^ ((row & 7) << 4);
        bfr[nf] = *(const bf16x8*)((const char*)lB[cur] + byte);
      }
#pragma unroll
      for (int mf = 0; mf < 4; mf++)
#pragma unroll
        for (int nf = 0; nf < 4; nf++)
          acc[mf][nf] = mfma16(af[mf], bfr[nf], acc[mf][nf]);
    }
    // single barrier per tile: writes target cur^1 (disjoint from this tile's
    // reads of cur); the previous barrier already retired all reads of cur^1.
    if (kt + 1 < NT) stage_write(cur ^ 1);
    __syncthreads();
    cur ^= 1;
  }

  const int row0 = bm * 128 + wr * 64;
  const int col0 = bn * 128 + wc * 64;
  if (MODE == 0){
#pragma unroll
    for (int nf = 0; nf < 4; nf++){
      int colb = col0 + nf * 16;
      float bv = bias[colb + l16];
      int which = colb >> 11;
      int h = (colb >> 7) & 15;
      int e = (colb & 127) + l16;
#pragma unroll
      for (int mf = 0; mf < 4; mf++){
#pragma unroll
        for (int r = 0; r < 4; r++){
          int row = row0 + mf * 16 + lhi * 4 + r;
          int b = row >> 11, t = row & 2047;
          float v = acc[mf][nf][r] + bv;
          size_t bh = (size_t)(b * 16 + h);
          if (which == 0)      qb[(bh * 2048 + t) * 128 + e] = f2b(v * 0.08838834764831845f);
          else if (which == 1) kb[(bh * 2048 + t) * 128 + e] = f2b(v);
          else                 vtb[(bh * 128 + e) * 2048 + t] = f2b(v);
        }
      }
    }
  } else {
#pragma unroll
    for (int nf = 0; nf < 4; nf++){
      int col = col0 + nf * 16 + l16;
      float bv = bias[col];
#pragma unroll
      for (int mf = 0; mf < 4; mf++){
#pragma unroll
        for (int r = 0; r < 4; r++){
          int row = row0 + mf * 16 + lhi * 4 + r;
          outp[(size_t)row * 2048 + col] = acc[mf][nf][r] + bv;
        }
      }
    }
  }
}

// ---------------- flash attention (non-causal), q pre-scaled ----------------
// grid: (L/128, B*H); 4 waves, each owns 32 q rows (2 m-frags). KV tiles of 64,
// K and V^T double-buffered in LDS, single barrier per tile. lsum via MFMA-ones.
// NOTE on addressing: the XOR swizzle ((row&7)<<4, bits 4-6) is ALWAYS applied
// to the complete intra-tile byte offset (rule #21 — must match the write side
// algebraically); only bit-11+ terms (mf*2048) may be added outside the XOR.
__global__ __launch_bounds__(256, 2) void attn_kernel(
    const unsigned short* __restrict__ q_buf,
    const unsigned short* __restrict__ k_buf,
    const unsigned short* __restrict__ vt_buf,
    unsigned short* __restrict__ attn_out)
{
  constexpr int L = 2048, E = 128, NT = L / 64;
  __shared__ short lK[2][64 * 128];
  __shared__ short lVT[2][128 * 64];
  __shared__ short lP[4][32 * 64];
  const int tid = threadIdx.x, lane = tid & 63, wid = tid >> 6;
  const int l16 = lane & 15, lhi = lane >> 4;
  const int bh = blockIdx.y;
  const int qbase = blockIdx.x * 128;
  const unsigned short* qp = q_buf + (size_t)bh * L * E;
  const unsigned short* kp = k_buf + (size_t)bh * L * E;
  const unsigned short* vp = vt_buf + (size_t)bh * E * L;

  // Q fragments: 32 q rows per wave, 2 m-frags
  bf16x8 qf[2][4];
#pragma unroll
  for (int mf = 0; mf < 2; mf++){
    int qrow = qbase + wid * 32 + mf * 16 + l16;
#pragma unroll
    for (int kk = 0; kk < 4; kk++)
      qf[mf][kk] = *(const bf16x8*)(qp + (size_t)qrow * E + kk * 32 + lhi * 8);
  }

  bf16x8 ones;
#pragma unroll
  for (int j = 0; j < 8; j++) ones[j] = (short)0x3F80;

  f32x4 z = {0.f, 0.f, 0.f, 0.f};
  f32x4 oacc[2][8];
#pragma unroll
  for (int mf = 0; mf < 2; mf++)
#pragma unroll
    for (int ne = 0; ne < 8; ne++) oacc[mf][ne] = z;
  f32x4 lacc[2] = {z, z};
  float mrow[2][4], m2[2][4];
#pragma unroll
  for (int mf = 0; mf < 2; mf++)
#pragma unroll
    for (int r = 0; r < 4; r++){ mrow[mf][r] = -1e30f; m2[mf][r] = 0.f; }

  // staging: loop-invariant global pointers + LDS write byte offsets
  const unsigned short* kptr[4]; const unsigned short* vptr[4];
  int kwr[4], vwr[4];
#pragma unroll
  for (int i = 0; i < 4; i++){
    int c = tid + 256 * i;
    { int row = c >> 4; kptr[i] = kp + (size_t)row * E + (c & 15) * 8;
      kwr[i] = (row * 256 + (c & 15) * 16) ^ ((row & 7) << 4); }
    { int row = c >> 3; vptr[i] = vp + (size_t)row * L + (c & 7) * 8;
      vwr[i] = (row * 128 + (c & 7) * 16) ^ ((row & 7) << 4); }
  }
  char* lPw = (char*)lP[wid];

  int4v kreg[4], vreg[4];
  auto stage_load = [&](int kt){
#pragma unroll
    for (int i = 0; i < 4; i++){
      kreg[i] = *(const int4v*)(kptr[i] + kt * 8192);
      vreg[i] = *(const int4v*)(vptr[i] + kt * 64);
    }
  };
  auto stage_write = [&](int buf){
    char* bK = (char*)lK[buf]; char* bV = (char*)lVT[buf];
#pragma unroll
    for (int i = 0; i < 4; i++){
      *(int4v*)(bK + kwr[i]) = kreg[i];
      *(int4v*)(bV + vwr[i]) = vreg[i];
    }
  };

  stage_load(0); stage_write(0); __syncthreads();
  int cur = 0;
  for (int kt = 0; kt < NT; ++kt){
    if (kt + 1 < NT) stage_load(kt + 1);
    const char* cK = (const char*)lK[cur];
    const char* cV = (const char*)lVT[cur];

    // S = Q K^T (q pre-scaled); sf[mf][nf]: rows q, cols keys
    f32x4 sf[2][4];
#pragma unroll
    for (int mf = 0; mf < 2; mf++)
#pragma unroll
      for (int nf = 0; nf < 4; nf++) sf[mf][nf] = z;
    __builtin_amdgcn_s_setprio(1);
#pragma unroll
    for (int kk = 0; kk < 4; kk++){
#pragma unroll
      for (int nf = 0; nf < 4; nf++){
        int key = nf * 16 + l16;
        int byte = (key * 256 + kk * 64 + lhi * 16) ^ ((key & 7) << 4);
        bf16x8 kb8 = *(const bf16x8*)(cK + byte);
#pragma unroll
        for (int mf = 0; mf < 2; mf++)
          sf[mf][nf] = mfma16(qf[mf][kk], kb8, sf[mf][nf]);
      }
    }
    __builtin_amdgcn_s_setprio(0);

    // row max (keys live across the 16-lane group; reduce over l16)
    float tmax[2][4];
#pragma unroll
    for (int mf = 0; mf < 2; mf++)
#pragma unroll
      for (int r = 0; r < 4; r++)
        tmax[mf][r] = fmaxf(fmaxf(sf[mf][0][r], sf[mf][1][r]),
                            fmaxf(sf[mf][2][r], sf[mf][3][r]));
#pragma unroll
    for (int off = 1; off < 16; off <<= 1){
#pragma unroll
      for (int mf = 0; mf < 2; mf++)
#pragma unroll
        for (int r = 0; r < 4; r++)
          tmax[mf][r] = fmaxf(tmax[mf][r], __shfl_xor(tmax[mf][r], off, 64));
    }

    // defer-max (T13): only rescale when some row's max grew by > 8
    bool ok = true;
#pragma unroll
    for (int mf = 0; mf < 2; mf++)
#pragma unroll
      for (int r = 0; r < 4; r++)
        ok = ok && (tmax[mf][r] <= mrow[mf][r] + 8.0f);
    if (!__all(ok)){
#pragma unroll
      for (int mf = 0; mf < 2; mf++){
        float alpha[4];
#pragma unroll
        for (int r = 0; r < 4; r++){
          float mn = fmaxf(mrow[mf][r], tmax[mf][r]);
          alpha[r] = __builtin_exp2f((mrow[mf][r] - mn) * LOG2E);
          mrow[mf][r] = mn; m2[mf][r] = mn * LOG2E;
        }
#pragma unroll
        for (int ne = 0; ne < 8; ne++)
#pragma unroll
          for (int r = 0; r < 4; r++)
            oacc[mf][ne][r] *= alpha[r];
#pragma unroll
        for (int r = 0; r < 4; r++) lacc[mf][r] *= alpha[r];
      }
    }

    // P = exp2(s*log2e - m2) -> per-wave LDS (bf16)
#pragma unroll
    for (int mf = 0; mf < 2; mf++)
#pragma unroll
      for (int nf = 0; nf < 4; nf++)
#pragma unroll
        for (int r = 0; r < 4; r++){
          float p = __builtin_exp2f(__builtin_fmaf(sf[mf][nf][r], LOG2E, -m2[mf][r]));
          int row = lhi * 4 + r;
          int byte = ((row * 128 + (nf * 16 + l16) * 2) ^ ((row & 7) << 4)) + mf * 2048;
          *(short*)(lPw + byte) = (short)f2bf(p);
        }

    // P A-fragments + lsum via MFMA-ones
    bf16x8 pa[2][2];
#pragma unroll
    for (int mf = 0; mf < 2; mf++)
#pragma unroll
      for (int kk2 = 0; kk2 < 2; kk2++){
        int byte = ((l16 * 128 + kk2 * 64 + lhi * 16) ^ ((l16 & 7) << 4)) + mf * 2048;
        pa[mf][kk2] = *(const bf16x8*)(lPw + byte);
      }
#pragma unroll
    for (int mf = 0; mf < 2; mf++)
#pragma unroll
      for (int kk2 = 0; kk2 < 2; kk2++)
        lacc[mf] = mfma16(pa[mf][kk2], ones, lacc[mf]);

    // PV: oacc += P @ V  (V^T tile rows are e)
    __builtin_amdgcn_s_setprio(1);
#pragma unroll
    for (int ne = 0; ne < 8; ne++){
#pragma unroll
      for (int kk2 = 0; kk2 < 2; kk2++){
        int e = ne * 16 + l16;
        int byte = (e * 128 + kk2 * 64 + lhi * 16) ^ ((e & 7) << 4);
        bf16x8 vb = *(const bf16x8*)(cV + byte);
#pragma unroll
        for (int mf = 0; mf < 2; mf++)
          oacc[mf][ne] = mfma16(pa[mf][kk2], vb, oacc[mf][ne]);
      }
    }
    __builtin_amdgcn_s_setprio(0);

    // single barrier per tile (writes go to cur^1, disjoint from reads of cur)
    if (kt + 1 < NT) stage_write(cur ^ 1);
    __syncthreads();
    cur ^= 1;
  }

  const int b = bh >> 4, h = bh & 15;
#pragma unroll
  for (int mf = 0; mf < 2; mf++){
    float rl[4];
#pragma unroll
    for (int r = 0; r < 4; r++) rl[r] = 1.0f / lacc[mf][r];
#pragma unroll
    for (int ne = 0; ne < 8; ne++){
#pragma unroll
      for (int r = 0; r < 4; r++){
        int row = qbase + wid * 32 + mf * 16 + lhi * 4 + r;
        float v = oacc[mf][ne][r] * rl[r];
        attn_out[((size_t)(b * L + row)) * 2048 + h * 128 + ne * 16 + l16] = f2b(v);
      }
    }
  }
}

extern "C" void kernel_launch(void* const* d_in, const int* in_sizes, int n_in,
                              void* d_out, int out_size, void* d_ws, size_t ws_size,
                              hipStream_t stream) {
  const float* x     = (const float*)d_in[0];
  const float* w_qkv = (const float*)d_in[1];
  const float* b_qkv = (const float*)d_in[2];
  const float* w_out = (const float*)d_in[3];
  const float* b_out = (const float*)d_in[4];
  float* out = (float*)d_out;

  unsigned short* ws = (unsigned short*)d_ws;
  unsigned short* xb    = ws;                               // 4096*2048
  unsigned short* wqkvT = xb    + (size_t)4096 * 2048;      // 6144*2048
  unsigned short* woutT = wqkvT + (size_t)6144 * 2048;      // 2048*2048
  unsigned short* qb    = woutT + (size_t)2048 * 2048;      // [2,16,2048,128]
  unsigned short* kb    = qb    + (size_t)2 * 16 * 2048 * 128;
  unsigned short* vtb   = kb    + (size_t)2 * 16 * 2048 * 128;  // [2,16,128,2048]
  unsigned short* attnb = vtb   + (size_t)2 * 16 * 2048 * 128;  // 4096*2048

  cast_bf16_kernel<<<2048, 256, 0, stream>>>((const float4*)x, (us4*)xb, (4096 * 2048) / 4);
  transpose_cast_kernel<<<dim3(96, 32), 256, 0, stream>>>(w_qkv, wqkvT, 2048, 6144);
  transpose_cast_kernel<<<dim3(32, 32), 256, 0, stream>>>(w_out, woutT, 2048, 2048);
  gemm_kernel<0><<<dim3(32, 48), 256, 0, stream>>>(xb, wqkvT, b_qkv, qb, kb, vtb, nullptr);
  attn_kernel<<<dim3(16, 32), 256, 0, stream>>>(qb, kb, vtb, attnb);
  gemm_kernel<1><<<dim3(32, 16), 256, 0, stream>>>(attnb, woutT, b_out, nullptr, nullptr, nullptr, out);
}

// Round 4
// 290.823 us; speedup vs baseline: 1.7193x; 1.7193x over previous
//
#include <hip/hip_runtime.h>

typedef __attribute__((ext_vector_type(8))) short bf16x8;
typedef __attribute__((ext_vector_type(4))) float f32x4;
typedef __attribute__((ext_vector_type(16))) float f32x16;
typedef __attribute__((ext_vector_type(4))) int int4v;
typedef __attribute__((ext_vector_type(4))) unsigned short us4;

#define LOG2E 1.4426950408889634f

__device__ __forceinline__ unsigned short f2b(float f){
  unsigned u = __builtin_bit_cast(unsigned, f);
  u = (u + 0x7fffu + ((u >> 16) & 1u)) >> 16;
  return (unsigned short)u;
}
// round-to-nearest (ties up) — 0.5 ulp, 2 VALU ops
__device__ __forceinline__ unsigned short f2bf(float f){
  unsigned u = __builtin_bit_cast(unsigned, f);
  return (unsigned short)((u + 0x8000u) >> 16);
}

__device__ __forceinline__ f32x4 mfma16(bf16x8 a, bf16x8 b, f32x4 c){
  return __builtin_amdgcn_mfma_f32_16x16x32_bf16(a, b, c, 0, 0, 0);
}
__device__ __forceinline__ f32x16 mfma32(bf16x8 a, bf16x8 b, f32x16 c){
  return __builtin_amdgcn_mfma_f32_32x32x16_bf16(a, b, c, 0, 0, 0);
}

typedef const __attribute__((address_space(1))) void* gas_t;
typedef __attribute__((address_space(3))) void* las_t;
__device__ __forceinline__ void glds16(const void* g, void* l){
  __builtin_amdgcn_global_load_lds((gas_t)g, (las_t)l, 16, 0, 0);
}

// ---------------- cast fp32 -> bf16 (vectorized) ----------------
__global__ __launch_bounds__(256) void cast_bf16_kernel(const float4* __restrict__ in,
                                                        us4* __restrict__ out, int n4){
  int i = blockIdx.x * 256 + threadIdx.x;
  int stride = gridDim.x * 256;
  for (; i < n4; i += stride){
    float4 v = in[i];
    us4 o; o.x = f2b(v.x); o.y = f2b(v.y); o.z = f2b(v.z); o.w = f2b(v.w);
    out[i] = o;
  }
}

// ---------------- transpose + cast: in[R][C] fp32 -> out[C][R] bf16 ----------------
__global__ __launch_bounds__(256) void transpose_cast_kernel(const float* __restrict__ in,
                                                             unsigned short* __restrict__ out,
                                                             int R, int C){
  __shared__ float tile[64][65];
  const int tid = threadIdx.x;
  const int c0 = blockIdx.x * 64, r0 = blockIdx.y * 64;
#pragma unroll
  for (int p = 0; p < 4; p++){
    int idx = p * 1024 + tid * 4;
    int rr = idx >> 6, cc = idx & 63;
    float4 v = *(const float4*)(in + (size_t)(r0 + rr) * C + (c0 + cc));
    tile[rr][cc+0] = v.x; tile[rr][cc+1] = v.y; tile[rr][cc+2] = v.z; tile[rr][cc+3] = v.w;
  }
  __syncthreads();
#pragma unroll
  for (int p = 0; p < 4; p++){
    int idx = p * 1024 + tid * 4;
    int crow = idx >> 6, rcol = idx & 63;
    us4 o;
    o.x = f2b(tile[rcol+0][crow]); o.y = f2b(tile[rcol+1][crow]);
    o.z = f2b(tile[rcol+2][crow]); o.w = f2b(tile[rcol+3][crow]);
    *(us4*)(out + (size_t)(c0 + crow) * R + (r0 + rcol)) = o;
  }
}

// ---------------- bf16 GEMM: C[M][N] = A[M][K] * BT[N][K]^T + bias ----------------
template<int MODE>
__global__ __launch_bounds__(256, 2) void gemm_kernel(
    const unsigned short* __restrict__ A,
    const unsigned short* __restrict__ BT,
    const float* __restrict__ bias,
    unsigned short* __restrict__ qb,
    unsigned short* __restrict__ kb,
    unsigned short* __restrict__ vtb,
    float* __restrict__ outp)
{
  constexpr int K = 2048;
  constexpr int NT = K / 64;
  __shared__ short lA[2][128 * 64];
  __shared__ short lB[2][128 * 64];
  const int tid = threadIdx.x, lane = tid & 63, wid = tid >> 6;
  const int l16 = lane & 15, lhi = lane >> 4;
  const int wr = wid >> 1, wc = wid & 1;
  const int bm = blockIdx.x, bn = blockIdx.y;

  const unsigned short* Abase = A + (size_t)bm * 128 * K;
  const unsigned short* Bbase = BT + (size_t)bn * 128 * K;

  int4v areg[4], breg[4];

  auto stage_load = [&](int kt){
#pragma unroll
    for (int i = 0; i < 4; i++){
      int c = tid + 256 * i;
      int row = c >> 3; int off8 = (c & 7) * 8;
      areg[i] = *(const int4v*)(Abase + (size_t)row * K + kt * 64 + off8);
      breg[i] = *(const int4v*)(Bbase + (size_t)row * K + kt * 64 + off8);
    }
  };
  auto stage_write = [&](int buf){
#pragma unroll
    for (int i = 0; i < 4; i++){
      int c = tid + 256 * i;
      int row = c >> 3;
      int byte = (row * 128 + (c & 7) * 16) ^ ((row & 7) << 4);
      *(int4v*)((char*)lA[buf] + byte) = areg[i];
      *(int4v*)((char*)lB[buf] + byte) = breg[i];
    }
  };

  f32x4 acc[4][4];
  f32x4 z = {0.f, 0.f, 0.f, 0.f};
#pragma unroll
  for (int i = 0; i < 4; i++)
#pragma unroll
    for (int j = 0; j < 4; j++) acc[i][j] = z;

  stage_load(0); stage_write(0); __syncthreads();
  int cur = 0;
  for (int kt = 0; kt < NT; ++kt){
    if (kt + 1 < NT) stage_load(kt + 1);
#pragma unroll
    for (int kk = 0; kk < 2; kk++){
      bf16x8 af[4], bfr[4];
#pragma unroll
      for (int mf = 0; mf < 4; mf++){
        int row = wr * 64 + mf * 16 + l16;
        int byte = (row * 128 + kk * 64 + lhi * 16) ^ ((row & 7) << 4);
        af[mf] = *(const bf16x8*)((const char*)lA[cur] + byte);
      }
#pragma unroll
      for (int nf = 0; nf < 4; nf++){
        int row = wc * 64 + nf * 16 + l16;
        int byte = (row * 128 + kk * 64 + lhi * 16) ^ ((row & 7) << 4);
        bfr[nf] = *(const bf16x8*)((const char*)lB[cur] + byte);
      }
#pragma unroll
      for (int mf = 0; mf < 4; mf++)
#pragma unroll
        for (int nf = 0; nf < 4; nf++)
          acc[mf][nf] = mfma16(af[mf], bfr[nf], acc[mf][nf]);
    }
    // single barrier per tile: writes target cur^1 (disjoint from this tile's
    // reads of cur); the previous barrier already retired all reads of cur^1.
    if (kt + 1 < NT) stage_write(cur ^ 1);
    __syncthreads();
    cur ^= 1;
  }

  const int row0 = bm * 128 + wr * 64;
  const int col0 = bn * 128 + wc * 64;
  if (MODE == 0){
#pragma unroll
    for (int nf = 0; nf < 4; nf++){
      int colb = col0 + nf * 16;
      float bv = bias[colb + l16];
      int which = colb >> 11;
      int h = (colb >> 7) & 15;
      int e = (colb & 127) + l16;
#pragma unroll
      for (int mf = 0; mf < 4; mf++){
#pragma unroll
        for (int r = 0; r < 4; r++){
          int row = row0 + mf * 16 + lhi * 4 + r;
          int b = row >> 11, t = row & 2047;
          float v = acc[mf][nf][r] + bv;
          size_t bh = (size_t)(b * 16 + h);
          if (which == 0)      qb[(bh * 2048 + t) * 128 + e] = f2b(v * 0.08838834764831845f);
          else if (which == 1) kb[(bh * 2048 + t) * 128 + e] = f2b(v);
          else                 vtb[(bh * 128 + e) * 2048 + t] = f2b(v);
        }
      }
    }
  } else {
#pragma unroll
    for (int nf = 0; nf < 4; nf++){
      int col = col0 + nf * 16 + l16;
      float bv = bias[col];
#pragma unroll
      for (int mf = 0; mf < 4; mf++){
#pragma unroll
        for (int r = 0; r < 4; r++){
          int row = row0 + mf * 16 + lhi * 4 + r;
          outp[(size_t)row * 2048 + col] = acc[mf][nf][r] + bv;
        }
      }
    }
  }
}

// ---------------- flash attention v2: 32x32 MFMA, swapped QK^T, in-reg softmax ----
// grid: 512 blocks (remapped); 4 waves; wave owns 32 q (one 32-col n-frag).
// S^T = mfma(K, Q): lane holds 32 S values for q = lane&31 -> row stats in-register.
// K/V staged global->LDS via global_load_lds with PRE-SWIZZLED global source
// (rule #21: linear dest + inverse-swizzled source + swizzled read).
// P never touches LDS: packed to bf16 pairs, cross-half exchange via shfl_xor(32).
__global__ __launch_bounds__(256, 2) void attn_kernel(
    const unsigned short* __restrict__ q_buf,
    const unsigned short* __restrict__ k_buf,
    const unsigned short* __restrict__ vt_buf,
    unsigned short* __restrict__ attn_out)
{
  constexpr int L = 2048, NT = L / 64;
  __shared__ short lK[2][64 * 128];   // [key][e] rows 256 B, swizzled ^((key&7)<<4)
  __shared__ short lVT[2][128 * 64];  // [e][key] rows 128 B, swizzled ^((e&7)<<4)
  const int tid = threadIdx.x, lane = tid & 63, wid = tid >> 6;
  const int l31 = lane & 31, lhi2 = lane >> 5;

  // XCD-locality remap: dispatch id d -> d%8 fixed per bh, so all 16 q-blocks
  // of one head share a single XCD's L2 (4 MB K/V working set = L2 size).
  const int d = blockIdx.y * 16 + blockIdx.x;
  const int bh = (d & 7) + 8 * ((d >> 3) & 3);
  const int qi = d >> 5;
  const int qbase = qi * 128;

  const unsigned short* qp = q_buf + (size_t)bh * L * 128;
  const char* kp2 = (const char*)(k_buf + (size_t)bh * L * 128);
  const char* vp2 = (const char*)(vt_buf + (size_t)bh * 128 * L);

  // Q B-fragments: n = q = qbase+wid*32+l31, k(e) = kk*16 + lhi2*8 + j
  bf16x8 qf[8];
  {
    const unsigned short* qr = qp + (size_t)(qbase + wid * 32 + l31) * 128 + lhi2 * 8;
#pragma unroll
    for (int kk = 0; kk < 8; kk++)
      qf[kk] = *(const bf16x8*)(qr + kk * 16);
  }

  // global_load_lds per-lane sources (loop-invariant), 1 KB chunk per inst
  const char* kgp[4]; const char* vgp[4];
  int kdst[4], vdst[4];
#pragma unroll
  for (int i = 0; i < 4; i++){
    int c = wid * 4 + i;                       // chunk 0..15
    { int row = c * 4 + (lane >> 4);           // key row (256 B rows)
      int col = ((lane & 15) * 16) ^ ((row & 7) << 4);
      kgp[i] = kp2 + row * 256 + col;          // + kt*16384
      kdst[i] = c * 1024; }
    { int e = c * 8 + (lane >> 3);             // e row (128 B rows)
      int col = ((lane & 7) * 16) ^ ((e & 7) << 4);
      vgp[i] = vp2 + (size_t)e * 4096 + col;   // + kt*128
      vdst[i] = c * 1024; }
  }

  auto stage = [&](int kt, int buf){
    char* bK = (char*)lK[buf]; char* bV = (char*)lVT[buf];
#pragma unroll
    for (int i = 0; i < 4; i++){
      glds16(kgp[i] + kt * 16384, bK + kdst[i]);
      glds16(vgp[i] + (size_t)kt * 128, bV + vdst[i]);
    }
  };

  f32x16 oacc[4];
#pragma unroll
  for (int nf = 0; nf < 4; nf++)
#pragma unroll
    for (int j = 0; j < 16; j++) oacc[nf][j] = 0.f;
  float m = -1e30f, ml2 = 0.f, lsum = 0.f;

  stage(0, 0);
  __syncthreads();
  int cur = 0;
  for (int kt = 0; kt < NT; ++kt){
    if (kt + 1 < NT) stage(kt + 1, cur ^ 1);
    const char* cK = (const char*)lK[cur];
    const char* cV = (const char*)lVT[cur];

    // S^T[key][q]: A = K-frags (m=key), B = Q (n=q). 2 mf x 8 kk MFMAs.
    f32x16 sf[2];
#pragma unroll
    for (int mf = 0; mf < 2; mf++)
#pragma unroll
      for (int j = 0; j < 16; j++) sf[mf][j] = 0.f;
    __builtin_amdgcn_s_setprio(1);
#pragma unroll
    for (int kk = 0; kk < 8; kk++){
#pragma unroll
      for (int mf = 0; mf < 2; mf++){
        int byte = ((l31 * 256 + kk * 32 + lhi2 * 16) ^ ((l31 & 7) << 4)) + mf * 8192;
        bf16x8 kf = *(const bf16x8*)(cK + byte);
        sf[mf] = mfma32(kf, qf[kk], sf[mf]);
      }
    }
    __builtin_amdgcn_s_setprio(0);

    // row max for q = l31: 32 in-register values + one cross-half hop
    float tm = sf[0][0];
#pragma unroll
    for (int mf = 0; mf < 2; mf++)
#pragma unroll
      for (int j = 0; j < 16; j++) tm = fmaxf(tm, sf[mf][j]);
    tm = fmaxf(tm, __shfl_xor(tm, 32, 64));

    // defer-max (T13)
    if (!__all(tm <= m + 8.0f)){
      float mn = fmaxf(m, tm);
      float alpha = __builtin_exp2f((m - mn) * LOG2E);
      m = mn; ml2 = mn * LOG2E;
      lsum *= alpha;
      // oacc rows are q = rowpat(reg,lhi2); gather that q's alpha
#pragma unroll
      for (int reg = 0; reg < 16; reg++){
        int row = (reg & 3) + 8 * (reg >> 2) + 4 * lhi2;
        float ar = __shfl(alpha, row | (lane & 32), 64);
#pragma unroll
        for (int nf = 0; nf < 4; nf++) oacc[nf][reg] *= ar;
      }
    }

    // P = exp2(s*log2e - m*log2e); in-register row-sum
    float pex[2][16];
    float rs = 0.f;
#pragma unroll
    for (int mf = 0; mf < 2; mf++)
#pragma unroll
      for (int j = 0; j < 16; j++){
        float p = __builtin_exp2f(__builtin_fmaf(sf[mf][j], LOG2E, -ml2));
        pex[mf][j] = p; rs += p;
      }
    rs += __shfl_xor(rs, 32, 64);
    lsum += rs;

    // pack P to bf16 pairs: W[mf][g][h] = keys {32mf + 8g + 4*lhi2 + 2h, +1}
    unsigned W[2][4][2];
#pragma unroll
    for (int mf = 0; mf < 2; mf++)
#pragma unroll
      for (int g = 0; g < 4; g++)
#pragma unroll
        for (int h = 0; h < 2; h++)
          W[mf][g][h] = (unsigned)f2bf(pex[mf][g * 4 + 2 * h]) |
                        ((unsigned)f2bf(pex[mf][g * 4 + 2 * h + 1]) << 16);

    // PV: A = P[q][key] assembled from W via cross-half exchange; B = V^T
    __builtin_amdgcn_s_setprio(1);
#pragma unroll
    for (int kk2 = 0; kk2 < 4; kk2++){
      const int mfp = kk2 >> 1, gA = 2 * (kk2 & 1), gB = gA + 1;
      unsigned A0 = W[mfp][gA][0], A1 = W[mfp][gA][1];
      unsigned B0 = W[mfp][gB][0], B1 = W[mfp][gB][1];
      unsigned own0 = lhi2 ? B0 : A0, own1 = lhi2 ? B1 : A1;
      unsigned snd0 = lhi2 ? A0 : B0, snd1 = lhi2 ? A1 : B1;
      unsigned rcv0 = (unsigned)__shfl_xor((int)snd0, 32, 64);
      unsigned rcv1 = (unsigned)__shfl_xor((int)snd1, 32, 64);
      int4v pw;
      pw.x = (int)(lhi2 ? rcv0 : own0);
      pw.y = (int)(lhi2 ? rcv1 : own1);
      pw.z = (int)(lhi2 ? own0 : rcv0);
      pw.w = (int)(lhi2 ? own1 : rcv1);
      bf16x8 pa = __builtin_bit_cast(bf16x8, pw);
#pragma unroll
      for (int nf = 0; nf < 4; nf++){
        int byte = ((l31 * 128 + kk2 * 32 + lhi2 * 16) ^ ((l31 & 7) << 4)) + nf * 4096;
        bf16x8 vb = *(const bf16x8*)(cV + byte);
        oacc[nf] = mfma32(pa, vb, oacc[nf]);
      }
    }
    __builtin_amdgcn_s_setprio(0);

    __syncthreads();   // drains glds (vmcnt) + retires all reads of cur
    cur ^= 1;
  }

  const int b = bh >> 4, h = bh & 15;
  float rl = 1.0f / lsum;
#pragma unroll
  for (int reg = 0; reg < 16; reg++){
    int row = (reg & 3) + 8 * (reg >> 2) + 4 * lhi2;
    float rr = __shfl(rl, row | (lane & 32), 64);
    size_t base = ((size_t)(b * L + qbase + wid * 32 + row)) * 2048 + h * 128 + l31;
#pragma unroll
    for (int nf = 0; nf < 4; nf++)
      attn_out[base + nf * 32] = f2b(oacc[nf][reg] * rr);
  }
}

extern "C" void kernel_launch(void* const* d_in, const int* in_sizes, int n_in,
                              void* d_out, int out_size, void* d_ws, size_t ws_size,
                              hipStream_t stream) {
  const float* x     = (const float*)d_in[0];
  const float* w_qkv = (const float*)d_in[1];
  const float* b_qkv = (const float*)d_in[2];
  const float* w_out = (const float*)d_in[3];
  const float* b_out = (const float*)d_in[4];
  float* out = (float*)d_out;

  unsigned short* ws = (unsigned short*)d_ws;
  unsigned short* xb    = ws;                               // 4096*2048
  unsigned short* wqkvT = xb    + (size_t)4096 * 2048;      // 6144*2048
  unsigned short* woutT = wqkvT + (size_t)6144 * 2048;      // 2048*2048
  unsigned short* qb    = woutT + (size_t)2048 * 2048;      // [2,16,2048,128]
  unsigned short* kb    = qb    + (size_t)2 * 16 * 2048 * 128;
  unsigned short* vtb   = kb    + (size_t)2 * 16 * 2048 * 128;  // [2,16,128,2048]
  unsigned short* attnb = vtb   + (size_t)2 * 16 * 2048 * 128;  // 4096*2048

  cast_bf16_kernel<<<2048, 256, 0, stream>>>((const float4*)x, (us4*)xb, (4096 * 2048) / 4);
  transpose_cast_kernel<<<dim3(96, 32), 256, 0, stream>>>(w_qkv, wqkvT, 2048, 6144);
  transpose_cast_kernel<<<dim3(32, 32), 256, 0, stream>>>(w_out, woutT, 2048, 2048);
  gemm_kernel<0><<<dim3(32, 48), 256, 0, stream>>>(xb, wqkvT, b_qkv, qb, kb, vtb, nullptr);
  attn_kernel<<<dim3(16, 32), 256, 0, stream>>>(qb, kb, vtb, attnb);
  gemm_kernel<1><<<dim3(32, 16), 256, 0, stream>>>(attnb, woutT, b_out, nullptr, nullptr, nullptr, out);
}

// Round 5
// 279.977 us; speedup vs baseline: 1.7859x; 1.0387x over previous
//
#include <hip/hip_runtime.h>

typedef __attribute__((ext_vector_type(8))) short bf16x8;
typedef __attribute__((ext_vector_type(4))) float f32x4;
typedef __attribute__((ext_vector_type(16))) float f32x16;
typedef __attribute__((ext_vector_type(4))) int int4v;
typedef __attribute__((ext_vector_type(4))) unsigned short us4;

#define LOG2E 1.4426950408889634f

__device__ __forceinline__ unsigned short f2b(float f){
  unsigned u = __builtin_bit_cast(unsigned, f);
  u = (u + 0x7fffu + ((u >> 16) & 1u)) >> 16;
  return (unsigned short)u;
}
// round-to-nearest (ties up) — 0.5 ulp, 2 VALU ops
__device__ __forceinline__ unsigned short f2bf(float f){
  unsigned u = __builtin_bit_cast(unsigned, f);
  return (unsigned short)((u + 0x8000u) >> 16);
}

__device__ __forceinline__ f32x4 mfma16(bf16x8 a, bf16x8 b, f32x4 c){
  return __builtin_amdgcn_mfma_f32_16x16x32_bf16(a, b, c, 0, 0, 0);
}
__device__ __forceinline__ f32x16 mfma32(bf16x8 a, bf16x8 b, f32x16 c){
  return __builtin_amdgcn_mfma_f32_32x32x16_bf16(a, b, c, 0, 0, 0);
}

typedef const __attribute__((address_space(1))) void* gas_t;
typedef __attribute__((address_space(3))) void* las_t;
__device__ __forceinline__ void glds16(const void* g, void* l){
  __builtin_amdgcn_global_load_lds((gas_t)g, (las_t)l, 16, 0, 0);
}

// ---------------- cast fp32 -> bf16 (vectorized) ----------------
__global__ __launch_bounds__(256) void cast_bf16_kernel(const float4* __restrict__ in,
                                                        us4* __restrict__ out, int n4){
  int i = blockIdx.x * 256 + threadIdx.x;
  int stride = gridDim.x * 256;
  for (; i < n4; i += stride){
    float4 v = in[i];
    us4 o; o.x = f2b(v.x); o.y = f2b(v.y); o.z = f2b(v.z); o.w = f2b(v.w);
    out[i] = o;
  }
}

// ---------------- transpose + cast: in[R][C] fp32 -> out[C][R] bf16 ----------------
__global__ __launch_bounds__(256) void transpose_cast_kernel(const float* __restrict__ in,
                                                             unsigned short* __restrict__ out,
                                                             int R, int C){
  __shared__ float tile[64][65];
  const int tid = threadIdx.x;
  const int c0 = blockIdx.x * 64, r0 = blockIdx.y * 64;
#pragma unroll
  for (int p = 0; p < 4; p++){
    int idx = p * 1024 + tid * 4;
    int rr = idx >> 6, cc = idx & 63;
    float4 v = *(const float4*)(in + (size_t)(r0 + rr) * C + (c0 + cc));
    tile[rr][cc+0] = v.x; tile[rr][cc+1] = v.y; tile[rr][cc+2] = v.z; tile[rr][cc+3] = v.w;
  }
  __syncthreads();
#pragma unroll
  for (int p = 0; p < 4; p++){
    int idx = p * 1024 + tid * 4;
    int crow = idx >> 6, rcol = idx & 63;
    us4 o;
    o.x = f2b(tile[rcol+0][crow]); o.y = f2b(tile[rcol+1][crow]);
    o.z = f2b(tile[rcol+2][crow]); o.w = f2b(tile[rcol+3][crow]);
    *(us4*)(out + (size_t)(c0 + crow) * R + (r0 + rcol)) = o;
  }
}

// ---------------- bf16 GEMM: C[M][N] = A[M][K] * BT[N][K]^T + bias ----------------
// Staging: global_load_lds width=16 (m97 structure), linear LDS dest
// (wave-uniform base + lane*16), PRE-SWIZZLED global source column
// ((lane&7)*16)^((lane>>3)<<4)  [rule #21: source perm == read perm].
template<int MODE>
__global__ __launch_bounds__(256, 2) void gemm_kernel(
    const unsigned short* __restrict__ A,
    const unsigned short* __restrict__ BT,
    const float* __restrict__ bias,
    unsigned short* __restrict__ qb,
    unsigned short* __restrict__ kb,
    unsigned short* __restrict__ vtb,
    float* __restrict__ outp)
{
  constexpr int K = 2048;
  constexpr int NT = K / 64;
  __shared__ short lA[2][128 * 64];
  __shared__ short lB[2][128 * 64];
  const int tid = threadIdx.x, lane = tid & 63, wid = tid >> 6;
  const int l16 = lane & 15, lhi = lane >> 4;
  const int wr = wid >> 1, wc = wid & 1;
  const int bm = blockIdx.x, bn = blockIdx.y;

  const char* Abase = (const char*)(A + (size_t)bm * 128 * K);
  const char* Bbase = (const char*)(BT + (size_t)bn * 128 * K);

  // per-inst loop-invariant source pointers + wave-uniform LDS dest offsets
  const char* agp[4]; const char* bgp[4];
  int dst[4];
#pragma unroll
  for (int i = 0; i < 4; i++){
    int c = wid * 4 + i;                 // chunk 0..15, 8 rows (1 KB) each
    int row = c * 8 + (lane >> 3);
    int col = ((lane & 7) * 16) ^ ((lane >> 3) << 4);   // row&7 == lane>>3
    agp[i] = Abase + (size_t)row * (K * 2) + col;       // + kt*128
    bgp[i] = Bbase + (size_t)row * (K * 2) + col;
    dst[i] = c * 1024;                   // HW adds lane*16
  }

  auto stage = [&](int kt, int buf){
    char* bA = (char*)lA[buf]; char* bB = (char*)lB[buf];
#pragma unroll
    for (int i = 0; i < 4; i++){
      glds16(agp[i] + kt * 128, bA + dst[i]);
      glds16(bgp[i] + kt * 128, bB + dst[i]);
    }
  };

  f32x4 acc[4][4];
  f32x4 z = {0.f, 0.f, 0.f, 0.f};
#pragma unroll
  for (int i = 0; i < 4; i++)
#pragma unroll
    for (int j = 0; j < 4; j++) acc[i][j] = z;

  stage(0, 0);
  __syncthreads();
  int cur = 0;
  for (int kt = 0; kt < NT; ++kt){
    if (kt + 1 < NT) stage(kt + 1, cur ^ 1);   // prefetch into cur^1
#pragma unroll
    for (int kk = 0; kk < 2; kk++){
      bf16x8 af[4], bfr[4];
#pragma unroll
      for (int mf = 0; mf < 4; mf++){
        int row = wr * 64 + mf * 16 + l16;
        int byte = (row * 128 + kk * 64 + lhi * 16) ^ ((row & 7) << 4);
        af[mf] = *(const bf16x8*)((const char*)lA[cur] + byte);
      }
#pragma unroll
      for (int nf = 0; nf < 4; nf++){
        int row = wc * 64 + nf * 16 + l16;
        int byte = (row * 128 + kk * 64 + lhi * 16) ^ ((row & 7) << 4);
        bfr[nf] = *(const bf16x8*)((const char*)lB[cur] + byte);
      }
      __builtin_amdgcn_s_setprio(1);
#pragma unroll
      for (int mf = 0; mf < 4; mf++)
#pragma unroll
        for (int nf = 0; nf < 4; nf++)
          acc[mf][nf] = mfma16(af[mf], bfr[nf], acc[mf][nf]);
      __builtin_amdgcn_s_setprio(0);
    }
    // single barrier per K-step: __syncthreads drains vmcnt (glds complete)
    // and retires this tile's reads; writes targeted cur^1 (disjoint).
    __syncthreads();
    cur ^= 1;
  }

  const int row0 = bm * 128 + wr * 64;
  const int col0 = bn * 128 + wc * 64;
  if (MODE == 0){
#pragma unroll
    for (int nf = 0; nf < 4; nf++){
      int colb = col0 + nf * 16;
      float bv = bias[colb + l16];
      int which = colb >> 11;
      int h = (colb >> 7) & 15;
      int e = (colb & 127) + l16;
#pragma unroll
      for (int mf = 0; mf < 4; mf++){
#pragma unroll
        for (int r = 0; r < 4; r++){
          int row = row0 + mf * 16 + lhi * 4 + r;
          int b = row >> 11, t = row & 2047;
          float v = acc[mf][nf][r] + bv;
          size_t bh = (size_t)(b * 16 + h);
          if (which == 0)      qb[(bh * 2048 + t) * 128 + e] = f2b(v * 0.08838834764831845f);
          else if (which == 1) kb[(bh * 2048 + t) * 128 + e] = f2b(v);
          else                 vtb[(bh * 128 + e) * 2048 + t] = f2b(v);
        }
      }
    }
  } else {
#pragma unroll
    for (int nf = 0; nf < 4; nf++){
      int col = col0 + nf * 16 + l16;
      float bv = bias[col];
#pragma unroll
      for (int mf = 0; mf < 4; mf++){
#pragma unroll
        for (int r = 0; r < 4; r++){
          int row = row0 + mf * 16 + lhi * 4 + r;
          outp[(size_t)row * 2048 + col] = acc[mf][nf][r] + bv;
        }
      }
    }
  }
}

// ---------------- flash attention v2: 32x32 MFMA, swapped QK^T, in-reg softmax ----
// grid: 512 blocks (remapped); 4 waves; wave owns 32 q (one 32-col n-frag).
// S^T = mfma(K, Q): lane holds 32 S values for q = lane&31 -> row stats in-register.
// K/V staged global->LDS via global_load_lds with PRE-SWIZZLED global source
// (rule #21: linear dest + inverse-swizzled source + swizzled read).
// P never touches LDS: packed to bf16 pairs, cross-half exchange via shfl_xor(32).
__global__ __launch_bounds__(256, 2) void attn_kernel(
    const unsigned short* __restrict__ q_buf,
    const unsigned short* __restrict__ k_buf,
    const unsigned short* __restrict__ vt_buf,
    unsigned short* __restrict__ attn_out)
{
  constexpr int L = 2048, NT = L / 64;
  __shared__ short lK[2][64 * 128];   // [key][e] rows 256 B, swizzled ^((key&7)<<4)
  __shared__ short lVT[2][128 * 64];  // [e][key] rows 128 B, swizzled ^((e&7)<<4)
  const int tid = threadIdx.x, lane = tid & 63, wid = tid >> 6;
  const int l31 = lane & 31, lhi2 = lane >> 5;

  // XCD-locality remap: dispatch id d -> d%8 fixed per bh, so all 16 q-blocks
  // of one head share a single XCD's L2 (4 MB K/V working set = L2 size).
  const int d = blockIdx.y * 16 + blockIdx.x;
  const int bh = (d & 7) + 8 * ((d >> 3) & 3);
  const int qi = d >> 5;
  const int qbase = qi * 128;

  const unsigned short* qp = q_buf + (size_t)bh * L * 128;
  const char* kp2 = (const char*)(k_buf + (size_t)bh * L * 128);
  const char* vp2 = (const char*)(vt_buf + (size_t)bh * 128 * L);

  // Q B-fragments: n = q = qbase+wid*32+l31, k(e) = kk*16 + lhi2*8 + j
  bf16x8 qf[8];
  {
    const unsigned short* qr = qp + (size_t)(qbase + wid * 32 + l31) * 128 + lhi2 * 8;
#pragma unroll
    for (int kk = 0; kk < 8; kk++)
      qf[kk] = *(const bf16x8*)(qr + kk * 16);
  }

  // global_load_lds per-lane sources (loop-invariant), 1 KB chunk per inst
  const char* kgp[4]; const char* vgp[4];
  int kdst[4], vdst[4];
#pragma unroll
  for (int i = 0; i < 4; i++){
    int c = wid * 4 + i;                       // chunk 0..15
    { int row = c * 4 + (lane >> 4);           // key row (256 B rows)
      int col = ((lane & 15) * 16) ^ ((row & 7) << 4);
      kgp[i] = kp2 + row * 256 + col;          // + kt*16384
      kdst[i] = c * 1024; }
    { int e = c * 8 + (lane >> 3);             // e row (128 B rows)
      int col = ((lane & 7) * 16) ^ ((e & 7) << 4);
      vgp[i] = vp2 + (size_t)e * 4096 + col;   // + kt*128
      vdst[i] = c * 1024; }
  }

  auto stage = [&](int kt, int buf){
    char* bK = (char*)lK[buf]; char* bV = (char*)lVT[buf];
#pragma unroll
    for (int i = 0; i < 4; i++){
      glds16(kgp[i] + kt * 16384, bK + kdst[i]);
      glds16(vgp[i] + (size_t)kt * 128, bV + vdst[i]);
    }
  };

  f32x16 oacc[4];
#pragma unroll
  for (int nf = 0; nf < 4; nf++)
#pragma unroll
    for (int j = 0; j < 16; j++) oacc[nf][j] = 0.f;
  float m = -1e30f, ml2 = 0.f, lsum = 0.f;

  stage(0, 0);
  __syncthreads();
  int cur = 0;
  for (int kt = 0; kt < NT; ++kt){
    if (kt + 1 < NT) stage(kt + 1, cur ^ 1);
    const char* cK = (const char*)lK[cur];
    const char* cV = (const char*)lVT[cur];

    // S^T[key][q]: A = K-frags (m=key), B = Q (n=q). 2 mf x 8 kk MFMAs.
    f32x16 sf[2];
#pragma unroll
    for (int mf = 0; mf < 2; mf++)
#pragma unroll
      for (int j = 0; j < 16; j++) sf[mf][j] = 0.f;
    __builtin_amdgcn_s_setprio(1);
#pragma unroll
    for (int kk = 0; kk < 8; kk++){
#pragma unroll
      for (int mf = 0; mf < 2; mf++){
        int byte = ((l31 * 256 + kk * 32 + lhi2 * 16) ^ ((l31 & 7) << 4)) + mf * 8192;
        bf16x8 kf = *(const bf16x8*)(cK + byte);
        sf[mf] = mfma32(kf, qf[kk], sf[mf]);
      }
    }
    __builtin_amdgcn_s_setprio(0);

    // row max for q = l31: 32 in-register values + one cross-half hop
    float tm = sf[0][0];
#pragma unroll
    for (int mf = 0; mf < 2; mf++)
#pragma unroll
      for (int j = 0; j < 16; j++) tm = fmaxf(tm, sf[mf][j]);
    tm = fmaxf(tm, __shfl_xor(tm, 32, 64));

    // defer-max (T13)
    if (!__all(tm <= m + 8.0f)){
      float mn = fmaxf(m, tm);
      float alpha = __builtin_exp2f((m - mn) * LOG2E);
      m = mn; ml2 = mn * LOG2E;
      lsum *= alpha;
      // oacc rows are q = rowpat(reg,lhi2); gather that q's alpha
#pragma unroll
      for (int reg = 0; reg < 16; reg++){
        int row = (reg & 3) + 8 * (reg >> 2) + 4 * lhi2;
        float ar = __shfl(alpha, row | (lane & 32), 64);
#pragma unroll
        for (int nf = 0; nf < 4; nf++) oacc[nf][reg] *= ar;
      }
    }

    // P = exp2(s*log2e - m*log2e); in-register row-sum
    float pex[2][16];
    float rs = 0.f;
#pragma unroll
    for (int mf = 0; mf < 2; mf++)
#pragma unroll
      for (int j = 0; j < 16; j++){
        float p = __builtin_exp2f(__builtin_fmaf(sf[mf][j], LOG2E, -ml2));
        pex[mf][j] = p; rs += p;
      }
    rs += __shfl_xor(rs, 32, 64);
    lsum += rs;

    // pack P to bf16 pairs: W[mf][g][h] = keys {32mf + 8g + 4*lhi2 + 2h, +1}
    unsigned W[2][4][2];
#pragma unroll
    for (int mf = 0; mf < 2; mf++)
#pragma unroll
      for (int g = 0; g < 4; g++)
#pragma unroll
        for (int h = 0; h < 2; h++)
          W[mf][g][h] = (unsigned)f2bf(pex[mf][g * 4 + 2 * h]) |
                        ((unsigned)f2bf(pex[mf][g * 4 + 2 * h + 1]) << 16);

    // PV: A = P[q][key] assembled from W via cross-half exchange; B = V^T
    __builtin_amdgcn_s_setprio(1);
#pragma unroll
    for (int kk2 = 0; kk2 < 4; kk2++){
      const int mfp = kk2 >> 1, gA = 2 * (kk2 & 1), gB = gA + 1;
      unsigned A0 = W[mfp][gA][0], A1 = W[mfp][gA][1];
      unsigned B0 = W[mfp][gB][0], B1 = W[mfp][gB][1];
      unsigned own0 = lhi2 ? B0 : A0, own1 = lhi2 ? B1 : A1;
      unsigned snd0 = lhi2 ? A0 : B0, snd1 = lhi2 ? A1 : B1;
      unsigned rcv0 = (unsigned)__shfl_xor((int)snd0, 32, 64);
      unsigned rcv1 = (unsigned)__shfl_xor((int)snd1, 32, 64);
      int4v pw;
      pw.x = (int)(lhi2 ? rcv0 : own0);
      pw.y = (int)(lhi2 ? rcv1 : own1);
      pw.z = (int)(lhi2 ? own0 : rcv0);
      pw.w = (int)(lhi2 ? own1 : rcv1);
      bf16x8 pa = __builtin_bit_cast(bf16x8, pw);
#pragma unroll
      for (int nf = 0; nf < 4; nf++){
        int byte = ((l31 * 128 + kk2 * 32 + lhi2 * 16) ^ ((l31 & 7) << 4)) + nf * 4096;
        bf16x8 vb = *(const bf16x8*)(cV + byte);
        oacc[nf] = mfma32(pa, vb, oacc[nf]);
      }
    }
    __builtin_amdgcn_s_setprio(0);

    __syncthreads();   // drains glds (vmcnt) + retires all reads of cur
    cur ^= 1;
  }

  const int b = bh >> 4, h = bh & 15;
  float rl = 1.0f / lsum;
#pragma unroll
  for (int reg = 0; reg < 16; reg++){
    int row = (reg & 3) + 8 * (reg >> 2) + 4 * lhi2;
    float rr = __shfl(rl, row | (lane & 32), 64);
    size_t base = ((size_t)(b * L + qbase + wid * 32 + row)) * 2048 + h * 128 + l31;
#pragma unroll
    for (int nf = 0; nf < 4; nf++)
      attn_out[base + nf * 32] = f2b(oacc[nf][reg] * rr);
  }
}

extern "C" void kernel_launch(void* const* d_in, const int* in_sizes, int n_in,
                              void* d_out, int out_size, void* d_ws, size_t ws_size,
                              hipStream_t stream) {
  const float* x     = (const float*)d_in[0];
  const float* w_qkv = (const float*)d_in[1];
  const float* b_qkv = (const float*)d_in[2];
  const float* w_out = (const float*)d_in[3];
  const float* b_out = (const float*)d_in[4];
  float* out = (float*)d_out;

  unsigned short* ws = (unsigned short*)d_ws;
  unsigned short* xb    = ws;                               // 4096*2048
  unsigned short* wqkvT = xb    + (size_t)4096 * 2048;      // 6144*2048
  unsigned short* woutT = wqkvT + (size_t)6144 * 2048;      // 2048*2048
  unsigned short* qb    = woutT + (size_t)2048 * 2048;      // [2,16,2048,128]
  unsigned short* kb    = qb    + (size_t)2 * 16 * 2048 * 128;
  unsigned short* vtb   = kb    + (size_t)2 * 16 * 2048 * 128;  // [2,16,128,2048]
  unsigned short* attnb = vtb   + (size_t)2 * 16 * 2048 * 128;  // 4096*2048

  cast_bf16_kernel<<<2048, 256, 0, stream>>>((const float4*)x, (us4*)xb, (4096 * 2048) / 4);
  transpose_cast_kernel<<<dim3(96, 32), 256, 0, stream>>>(w_qkv, wqkvT, 2048, 6144);
  transpose_cast_kernel<<<dim3(32, 32), 256, 0, stream>>>(w_out, woutT, 2048, 2048);
  gemm_kernel<0><<<dim3(32, 48), 256, 0, stream>>>(xb, wqkvT, b_qkv, qb, kb, vtb, nullptr);
  attn_kernel<<<dim3(16, 32), 256, 0, stream>>>(qb, kb, vtb, attnb);
  gemm_kernel<1><<<dim3(32, 16), 256, 0, stream>>>(attnb, woutT, b_out, nullptr, nullptr, nullptr, out);
}